// Round 7
// baseline (7093.748 us; speedup 1.0000x reference)
//
#include <hip/hip_runtime.h>
#include <hip/hip_bf16.h>

typedef __attribute__((ext_vector_type(8))) short bhalf8;
typedef __attribute__((ext_vector_type(4))) float fvec4;
typedef __attribute__((ext_vector_type(4))) unsigned u32x4;

static __device__ __forceinline__ unsigned short f2bf(float f) {
  unsigned u = __builtin_bit_cast(unsigned, f);
  u = (u + 0x7fffu + ((u >> 16) & 1u)) >> 16;   // round-to-nearest-even
  return (unsigned short)u;
}
static __device__ __forceinline__ float tanh_fast(float x) {
  x = fminf(12.f, fmaxf(-12.f, x));
  float e = __expf(2.f * x);
  return (e - 1.f) / (e + 1.f);
}
static __device__ __forceinline__ fvec4 tanh4(fvec4 v) {
  fvec4 r;
  r[0] = tanh_fast(v[0]); r[1] = tanh_fast(v[1]);
  r[2] = tanh_fast(v[2]); r[3] = tanh_fast(v[3]);
  return r;
}
static __device__ __forceinline__ bhalf8 load_w8(const float* p) {
  fvec4 a = *(const fvec4*)p;
  fvec4 b = *(const fvec4*)(p + 4);
  bhalf8 r;
  r[0] = (short)f2bf(a[0]); r[1] = (short)f2bf(a[1]);
  r[2] = (short)f2bf(a[2]); r[3] = (short)f2bf(a[3]);
  r[4] = (short)f2bf(b[0]); r[5] = (short)f2bf(b[1]);
  r[6] = (short)f2bf(b[2]); r[7] = (short)f2bf(b[3]);
  return r;
}

// ---- fabric-coherent accesses (sc0 sc1): the ONLY tier proven coherent+deadlock-free
// ---- on this part (round-4 evidence; round-5's sc0-only tier hung in the poll).
// ---- HAZARD NOTE (round-6 lesson): deferred-wait asm loads must keep their output
// ---- register window SMALL (<=16 x u32x4 proven); large windows risk the allocator
// ---- copying/spilling a pending load destination before the vmcnt -> stale data.
static __device__ __forceinline__ void st_short_coh(unsigned short* p, unsigned v) {
  asm volatile("global_store_short %0, %1, off sc0 sc1" :: "v"(p), "v"(v) : "memory");
}
static __device__ __forceinline__ void st_f32_coh(float* p, float v) {
  asm volatile("global_store_dword %0, %1, off sc0 sc1" :: "v"(p), "v"(v) : "memory");
}
static __device__ __forceinline__ void st_u32_coh(unsigned* p, unsigned v) {
  asm volatile("global_store_dword %0, %1, off sc0 sc1" :: "v"(p), "v"(v) : "memory");
}
static __device__ __forceinline__ u32x4 ld16_coh(const void* p) {
  u32x4 v;
  asm volatile("global_load_dwordx4 %0, %1, off sc0 sc1" : "=v"(v) : "v"(p) : "memory");
  return v;
}
static __device__ __forceinline__ unsigned ld_u32_coh(const unsigned* p) {
  unsigned v;
  asm volatile("global_load_dword %0, %1, off sc0 sc1\n\ts_waitcnt vmcnt(0)"
               : "=v"(v) : "v"(p) : "memory");
  return v;
}
static __device__ __forceinline__ float ld_f32_coh(const float* p) {
  float v;
  asm volatile("global_load_dword %0, %1, off sc0 sc1\n\ts_waitcnt vmcnt(0)"
               : "=v"(v) : "v"(p) : "memory");
  return v;
}

#define MFMA16(a, b, c) __builtin_amdgcn_mfma_f32_16x16x32_bf16((a), (b), (c), 0, 0, 0)

// Persistent kernel, 256 WGs x 256 thr, 1 WG/CU (160 KiB LDS) -> grid HW-resident,
// group-local spin barriers safe. WG=(grp: 32 batch rows, memb: 64 H-cols).
// Critical path per step: poll -> stage z12 -> Wrec1 GEMM -> z12 store -> flag.
// z2 update (needed only at even steps, from >=2-step-old state) is computed in the
// SLACK after the flag of the preceding odd step. z2 slice kept in registers.
extern "C" __global__ void __launch_bounds__(256, 1)
alarm_rnn_persist(const float* __restrict__ X, const float* __restrict__ Win1,
                  const float* __restrict__ bin1, const float* __restrict__ Wrec1,
                  const float* __restrict__ Win2, const float* __restrict__ bin2,
                  const float* __restrict__ Wrec2, const float* __restrict__ Wout,
                  const float* __restrict__ bout, float* __restrict__ out,
                  unsigned* flags, unsigned short* gbuf0, unsigned short* gbuf1,
                  unsigned short* z2b0, unsigned short* z2b1, float* z1buf)
{
  constexpr int kL = 512, kI = 256, kH = 1024;
  // LDS map: [0,64K) z12 | [64K,96K) X ping-pong (2 x 16K) | [96K,160K) z2 stage
  extern __shared__ char smem[];

  const int tid = threadIdx.x, bid = blockIdx.x;
  const int grp = bid >> 4, memb = bid & 15;
  const int lane = tid & 63;
  const int row16 = lane & 15, kq = lane >> 4;
  const int sw = (row16 & 7) << 4;
  const int hcol = memb * 64 + (tid >> 6) * 16 + row16;
  const int brow0 = grp * 32;

  // ---- one-time: weights -> registers (B-fragment: lane holds W[hcol, kq*8+j (+32*kk)]) ----
  bhalf8 w1[32], w2[32], wi1[8], wi2[8];
  {
    const float* p1 = Wrec1 + (size_t)hcol * kH + kq * 8;
    const float* p2 = Wrec2 + (size_t)hcol * kH + kq * 8;
#pragma unroll
    for (int kk = 0; kk < 32; ++kk) {
      w1[kk] = load_w8(p1 + kk * 32);
      w2[kk] = load_w8(p2 + kk * 32);
    }
    const float* q1 = Win1 + (size_t)hcol * kI + kq * 8;
    const float* q2 = Win2 + (size_t)hcol * kI + kq * 8;
#pragma unroll
    for (int kk = 0; kk < 8; ++kk) {
      wi1[kk] = load_w8(q1 + kk * 32);
      wi2[kk] = load_w8(q2 + kk * 32);
    }
  }
  const float bv1 = bin1[hcol];
  const float bv2 = bin2[hcol];

  // ---- prologue: stage X(0), X(1); compute Z2[0] = tanh(b2 + Win2*X(0)); publish it ----
  {
    int r = tid >> 3, q = tid & 7;
#pragma unroll
    for (int p = 0; p < 2; ++p) {
      const float* xp = X + (size_t)(brow0 + r) * (kL * kI) + (size_t)p * kI;
      fvec4 xv[8];
#pragma unroll
      for (int j = 0; j < 8; ++j) xv[j] = *(const fvec4*)(xp + q * 4 + j * 32);
#pragma unroll
      for (int j = 0; j < 8; ++j) {
        int i0 = q * 4 + j * 32;
        ushort4 pk;
        pk.x = f2bf(xv[j][0]); pk.y = f2bf(xv[j][1]);
        pk.z = f2bf(xv[j][2]); pk.w = f2bf(xv[j][3]);
        *(ushort4*)(smem + 65536 + p * 16384 + (r << 9) + ((i0 * 2) ^ ((r & 7) << 4))) = pk;
      }
    }
  }
  __syncthreads();
  fvec4 z2c0, z2c1;
  {
    fvec4 b0 = {bv2, bv2, bv2, bv2}, b1 = b0;
#pragma unroll
    for (int kk = 0; kk < 8; ++kk) {
      int cb = kk * 64 + kq * 16;
      bhalf8 a0 = *(const bhalf8*)(smem + 65536 + (row16 << 9) + (cb ^ sw));
      bhalf8 a1 = *(const bhalf8*)(smem + 65536 + ((16 + row16) << 9) + (cb ^ sw));
      b0 = MFMA16(a0, wi2[kk], b0);
      b1 = MFMA16(a1, wi2[kk], b1);
    }
    z2c0 = tanh4(b0);
    z2c1 = tanh4(b1);
#pragma unroll
    for (int i = 0; i < 4; ++i) {
      st_short_coh(z2b0 + (size_t)(brow0 + kq * 4 + i) * kH + hcol, f2bf(z2c0[i]));
      st_short_coh(z2b0 + (size_t)(brow0 + 16 + kq * 4 + i) * kH + hcol, f2bf(z2c1[i]));
    }
  }

  for (int l = 0; l < kL; ++l) {
    // ---- A: issue z12(l) loads; overlap Win1*X(l) MFMAs; then LDS-write z12 ----
    u32x4 ztmp[16];
    {
      const unsigned short* zsrc = (l & 1) ? gbuf1 : gbuf0;
#pragma unroll
      for (int it = 0; it < 16; ++it) {
        int c = it * 256 + tid;
        int r = c >> 7, cb = (c & 127) * 16;
        ztmp[it] = ld16_coh((const char*)zsrc + (((size_t)(brow0 + r)) << 11) + cb);
      }
    }
    const char* xb = smem + 65536 + ((l & 1) << 14);
    fvec4 acc0 = {bv1, bv1, bv1, bv1}, acc1 = acc0;
#pragma unroll
    for (int kk = 0; kk < 8; ++kk) {
      int cb = kk * 64 + kq * 16;
      bhalf8 a0 = *(const bhalf8*)(xb + (row16 << 9) + (cb ^ sw));
      bhalf8 a1 = *(const bhalf8*)(xb + ((16 + row16) << 9) + (cb ^ sw));
      acc0 = MFMA16(a0, wi1[kk], acc0);
      acc1 = MFMA16(a1, wi1[kk], acc1);
    }
    __builtin_amdgcn_sched_barrier(0);
    asm volatile("s_waitcnt vmcnt(0)" ::: "memory");
    __builtin_amdgcn_sched_barrier(0);
#pragma unroll
    for (int it = 0; it < 16; ++it) {
      int c = it * 256 + tid;
      int r = c >> 7, cb = (c & 127) * 16;
      *(u32x4*)(smem + (r << 11) + (cb ^ ((r & 7) << 4))) = ztmp[it];
    }
    __syncthreads();  // #1

    // ---- B: z1 = tanh(acc + Wrec1 * z12) ----
#pragma unroll
    for (int kk = 0; kk < 32; ++kk) {
      int cb = kk * 64 + kq * 16;
      bhalf8 a0 = *(const bhalf8*)(smem + (row16 << 11) + (cb ^ sw));
      bhalf8 a1 = *(const bhalf8*)(smem + ((16 + row16) << 11) + (cb ^ sw));
      acc0 = MFMA16(a0, w1[kk], acc0);
      acc1 = MFMA16(a1, w1[kk], acc1);
    }
    fvec4 z1n0 = tanh4(acc0), z1n1 = tanh4(acc1);

    // ---- C: publish z12 = z1 + z2cur (C/D layout: col=row16->hcol, row=kq*4+i) ----
    if (l < kL - 1) {
      unsigned short* dst = (l & 1) ? gbuf0 : gbuf1;
#pragma unroll
      for (int i = 0; i < 4; ++i) {
        st_short_coh(dst + (size_t)(brow0 + kq * 4 + i) * kH + hcol, f2bf(z1n0[i] + z2c0[i]));
        st_short_coh(dst + (size_t)(brow0 + 16 + kq * 4 + i) * kH + hcol, f2bf(z1n1[i] + z2c1[i]));
      }
    } else {
#pragma unroll
      for (int i = 0; i < 4; ++i) {
        st_f32_coh(z1buf + (size_t)(brow0 + kq * 4 + i) * kH + hcol, z1n0[i]);
        st_f32_coh(z1buf + (size_t)(brow0 + 16 + kq * 4 + i) * kH + hcol, z1n1[i]);
      }
    }
    asm volatile("s_waitcnt vmcnt(0)" ::: "memory");
    __syncthreads();  // #2: all waves' exchange stores drained
    if (tid == 0) st_u32_coh(flags + grp * 16 + memb, (unsigned)(l + 1));

    // ---- D: issue X(l+2) input loads (slack; normal cached path) ----
    fvec4 xv[8];
    const int xr = tid >> 3, xq = tid & 7;
    if (l + 2 < kL) {
      const float* xp = X + (size_t)(brow0 + xr) * (kL * kI) + (size_t)(l + 2) * kI;
#pragma unroll
      for (int j = 0; j < 8; ++j) xv[j] = *(const fvec4*)(xp + xq * 4 + j * 32);
    }

    // ---- E (odd l): slack z2 work — stage Z2[e], compute Z2[e+1] for steps l+1,l+2 ----
    if ((l & 1) && l < kL - 1) {
      const int e = (l - 1) >> 1;
      const unsigned short* z2src = (e & 1) ? z2b1 : z2b0;
      u32x4 zt[16];
#pragma unroll
      for (int it = 0; it < 16; ++it) {
        int c = it * 256 + tid;
        int r = c >> 7, cb = (c & 127) * 16;
        zt[it] = ld16_coh((const char*)z2src + (((size_t)(brow0 + r)) << 11) + cb);
      }
      const char* xb1 = smem + 65536 + (((l + 1) & 1) << 14);
      fvec4 b0 = {bv2, bv2, bv2, bv2}, b1 = b0;
#pragma unroll
      for (int kk = 0; kk < 8; ++kk) {
        int cb = kk * 64 + kq * 16;
        bhalf8 a0 = *(const bhalf8*)(xb1 + (row16 << 9) + (cb ^ sw));
        bhalf8 a1 = *(const bhalf8*)(xb1 + ((16 + row16) << 9) + (cb ^ sw));
        b0 = MFMA16(a0, wi2[kk], b0);
        b1 = MFMA16(a1, wi2[kk], b1);
      }
      __builtin_amdgcn_sched_barrier(0);
      asm volatile("s_waitcnt vmcnt(0)" ::: "memory");  // z2 stage + X(l+2) loads done
      __builtin_amdgcn_sched_barrier(0);
#pragma unroll
      for (int it = 0; it < 16; ++it) {
        int c = it * 256 + tid;
        int r = c >> 7, cb = (c & 127) * 16;
        *(u32x4*)(smem + 98304 + (r << 11) + (cb ^ ((r & 7) << 4))) = zt[it];
      }
      if (l + 2 < kL) {  // X(l+2) -> LDS buf (l&1), dead since phase A
#pragma unroll
        for (int j = 0; j < 8; ++j) {
          int i0 = xq * 4 + j * 32;
          ushort4 pk;
          pk.x = f2bf(xv[j][0]); pk.y = f2bf(xv[j][1]);
          pk.z = f2bf(xv[j][2]); pk.w = f2bf(xv[j][3]);
          *(ushort4*)(smem + 65536 + ((l & 1) << 14) + (xr << 9) + ((i0 * 2) ^ ((xr & 7) << 4))) = pk;
        }
      }
      __syncthreads();  // #3: z2 stage visible
#pragma unroll
      for (int kk = 0; kk < 32; ++kk) {
        int cb = kk * 64 + kq * 16;
        bhalf8 a0 = *(const bhalf8*)(smem + 98304 + (row16 << 11) + (cb ^ sw));
        bhalf8 a1 = *(const bhalf8*)(smem + 98304 + ((16 + row16) << 11) + (cb ^ sw));
        b0 = MFMA16(a0, w2[kk], b0);
        b1 = MFMA16(a1, w2[kk], b1);
      }
      z2c0 = tanh4(b0);
      z2c1 = tanh4(b1);
      unsigned short* z2dst = ((e + 1) & 1) ? z2b1 : z2b0;
#pragma unroll
      for (int i = 0; i < 4; ++i) {
        st_short_coh(z2dst + (size_t)(brow0 + kq * 4 + i) * kH + hcol, f2bf(z2c0[i]));
        st_short_coh(z2dst + (size_t)(brow0 + 16 + kq * 4 + i) * kH + hcol, f2bf(z2c1[i]));
      }
    } else if (l + 2 < kL) {
      // even iter: just finish X(l+2) -> LDS (compiler inserts the wait on xv)
#pragma unroll
      for (int j = 0; j < 8; ++j) {
        int i0 = xq * 4 + j * 32;
        ushort4 pk;
        pk.x = f2bf(xv[j][0]); pk.y = f2bf(xv[j][1]);
        pk.z = f2bf(xv[j][2]); pk.w = f2bf(xv[j][3]);
        *(ushort4*)(smem + 65536 + ((l & 1) << 14) + (xr << 9) + ((i0 * 2) ^ ((xr & 7) << 4))) = pk;
      }
    }

    // ---- F: poll sibling flags for step l+1 ----
    {
      const unsigned tgt = (unsigned)(l + 1);
      const unsigned* fp = flags + grp * 16 + (lane & 15);
      for (;;) {
        unsigned v = (lane < 16) ? ld_u32_coh(fp) : tgt;
        bool ok = (lane >= 16) || ((lane & 15) == memb) || (v >= tgt);
        if (__all(ok)) break;
        __builtin_amdgcn_s_sleep(1);
      }
      __builtin_amdgcn_sched_barrier(0);
    }
  }

  // ---- epilogue: out[b] = tanh(z1[b,:] . Wout + bout), one WG per group ----
  // Round-4-proven pattern: per-load FUSED vmcnt (no deferred asm-load register
  // window -> no spill-before-wait hazard). Runs once; latency irrelevant.
  if (memb == 0) {
    int r = tid >> 3, q = tid & 7;
    const float* zr = z1buf + (size_t)(brow0 + r) * kH;
    float s = 0.f;
    for (int h = q * 128; h < q * 128 + 128; ++h) s += ld_f32_coh(zr + h) * Wout[h];
    s += __shfl_xor(s, 1);
    s += __shfl_xor(s, 2);
    s += __shfl_xor(s, 4);
    if (q == 0) out[brow0 + r] = tanh_fast(s + bout[0]);
  }
}

extern "C" void kernel_launch(void* const* d_in, const int* in_sizes, int n_in,
                              void* d_out, int out_size, void* d_ws, size_t ws_size,
                              hipStream_t stream) {
  const float* X = (const float*)d_in[0];
  const float* Win1 = (const float*)d_in[1];
  const float* bin1 = (const float*)d_in[2];
  const float* Wrec1 = (const float*)d_in[3];
  const float* Win2 = (const float*)d_in[4];
  const float* bin2 = (const float*)d_in[5];
  const float* Wrec2 = (const float*)d_in[6];
  const float* Wout = (const float*)d_in[7];
  const float* bout = (const float*)d_in[8];
  float* out = (float*)d_out;

  char* ws = (char*)d_ws;
  unsigned* flags = (unsigned*)ws;                                   // 256 dwords
  unsigned short* gbuf0 = (unsigned short*)(ws + 4096);              // 1 MB z12 ping
  unsigned short* gbuf1 = (unsigned short*)(ws + 4096 + (1 << 20));  // 1 MB z12 pong
  unsigned short* z2b0 = (unsigned short*)(ws + 4096 + (2 << 20));   // 1 MB Z2 even
  unsigned short* z2b1 = (unsigned short*)(ws + 4096 + (3 << 20));   // 1 MB Z2 odd
  float* z1buf = (float*)(ws + 4096 + (4 << 20));                    // 2 MB final z1 (f32)

  (void)hipMemsetAsync(flags, 0, 4096, stream);
  (void)hipMemsetAsync(gbuf0, 0, (size_t)512 * 1024 * 2, stream);  // z12(l=0) = 0

  (void)hipFuncSetAttribute((const void*)alarm_rnn_persist,
                            hipFuncAttributeMaxDynamicSharedMemorySize, 163840);

  alarm_rnn_persist<<<dim3(256), dim3(256), 163840, stream>>>(
      X, Win1, bin1, Wrec1, Win2, bin2, Wrec2, Wout, bout, out,
      flags, gbuf0, gbuf1, z2b0, z2b1, z1buf);
}

// Round 9
// 6382.452 us; speedup vs baseline: 1.1114x; 1.1114x over previous
//
#include <hip/hip_runtime.h>
#include <hip/hip_bf16.h>

typedef __attribute__((ext_vector_type(8))) short bhalf8;
typedef __attribute__((ext_vector_type(4))) float fvec4;

static __device__ __forceinline__ unsigned short f2bf(float f) {
  unsigned u = __builtin_bit_cast(unsigned, f);
  u = (u + 0x7fffu + ((u >> 16) & 1u)) >> 16;   // round-to-nearest-even
  return (unsigned short)u;
}
static __device__ __forceinline__ float tanh_fast(float x) {
  x = fminf(12.f, fmaxf(-12.f, x));
  float e = __expf(2.f * x);
  return (e - 1.f) / (e + 1.f);
}
static __device__ __forceinline__ fvec4 tanh4(fvec4 v) {
  fvec4 r;
  r[0] = tanh_fast(v[0]); r[1] = tanh_fast(v[1]);
  r[2] = tanh_fast(v[2]); r[3] = tanh_fast(v[3]);
  return r;
}
static __device__ __forceinline__ bhalf8 load_w8(const float* p) {
  fvec4 a = *(const fvec4*)p;
  fvec4 b = *(const fvec4*)(p + 4);
  bhalf8 r;
  r[0] = (short)f2bf(a[0]); r[1] = (short)f2bf(a[1]);
  r[2] = (short)f2bf(a[2]); r[3] = (short)f2bf(a[3]);
  r[4] = (short)f2bf(b[0]); r[5] = (short)f2bf(b[1]);
  r[6] = (short)f2bf(b[2]); r[7] = (short)f2bf(b[3]);
  return r;
}

// ---- fabric-coherent (sc0 sc1) accesses: the only tier proven coherent+deadlock-
// ---- free here (rounds 4/5). SESSION RULES: (1) no asm-load destination window may
// ---- cross a GEMM (round-6 stale data, round-8 abort); (2) exchange staging goes
// ---- global->LDS via global_load_lds (zero VGPR window).
static __device__ __forceinline__ void st_short_coh(unsigned short* p, unsigned v) {
  asm volatile("global_store_short %0, %1, off sc0 sc1" :: "v"(p), "v"(v) : "memory");
}
static __device__ __forceinline__ void st_f32_coh(float* p, float v) {
  asm volatile("global_store_dword %0, %1, off sc0 sc1" :: "v"(p), "v"(v) : "memory");
}
static __device__ __forceinline__ void st_u32_coh(unsigned* p, unsigned v) {
  asm volatile("global_store_dword %0, %1, off sc0 sc1" :: "v"(p), "v"(v) : "memory");
}
static __device__ __forceinline__ unsigned ld_u32_coh(const unsigned* p) {
  unsigned v;
  asm volatile("global_load_dword %0, %1, off sc0 sc1\n\ts_waitcnt vmcnt(0)"
               : "=v"(v) : "v"(p) : "memory");
  return v;
}
static __device__ __forceinline__ float ld_f32_coh(const float* p) {
  float v;
  asm volatile("global_load_dword %0, %1, off sc0 sc1\n\ts_waitcnt vmcnt(0)"
               : "=v"(v) : "v"(p) : "memory");
  return v;
}
// direct global->LDS, 16B/lane, CPol 0x11 = SC0|SC1 (bypass L1 + XCD-L2).
static __device__ __forceinline__ void gll16_coh(const void* g, void* lds) {
  __builtin_amdgcn_global_load_lds(
      (const __attribute__((address_space(1))) void*)g,
      (__attribute__((address_space(3))) void*)lds, 16, 0, 0x11);
}

#define MFMA16(a, b, c) __builtin_amdgcn_mfma_f32_16x16x32_bf16((a), (b), (c), 0, 0, 0)

// Persistent kernel, 256 WGs x 256 thr, 1 WG/CU -> grid HW-resident, spin safe.
// WG=(grp: 32 batch rows, memb: 64 H-cols). Round-4 protocol exactly; staging via
// global_load_lds with source-side XOR swizzle (LDS dest linear, rule #21): on even
// steps z12+z2 issues go out together -> ONE overlapped MALL round trip, Win*X MFMAs
// under the load shadow (X pre-staged in LDS ping-pong, prefetched post-flag).
extern "C" __global__ void __launch_bounds__(256, 1)
alarm_rnn_persist(const float* __restrict__ X, const float* __restrict__ Win1,
                  const float* __restrict__ bin1, const float* __restrict__ Wrec1,
                  const float* __restrict__ Win2, const float* __restrict__ bin2,
                  const float* __restrict__ Wrec2, const float* __restrict__ Wout,
                  const float* __restrict__ bout, float* __restrict__ out,
                  unsigned* flags, unsigned short* gbuf0, unsigned short* gbuf1,
                  unsigned short* z2b0, unsigned short* z2b1, float* z1buf)
{
  constexpr int kL = 512, kI = 256, kH = 1024;
  // LDS: [0,64K) z12 | [64K,128K) z2 | [128K,160K) X ping-pong (2 x 16K)
  extern __shared__ char smem[];

  const int tid = threadIdx.x, bid = blockIdx.x;
  const int grp = bid >> 4, memb = bid & 15;
  const int lane = tid & 63, w = tid >> 6;
  const int row16 = lane & 15, kq = lane >> 4;
  const int sw = (row16 & 7) << 4;
  const int hcol = memb * 64 + w * 16 + row16;
  const int brow0 = grp * 32;

  // ---- one-time: weights -> registers (B-fragment: lane holds W[hcol, kq*8+j (+32*kk)]) ----
  bhalf8 w1[32], w2[32], wi1[8], wi2[8];
  {
    const float* p1 = Wrec1 + (size_t)hcol * kH + kq * 8;
    const float* p2 = Wrec2 + (size_t)hcol * kH + kq * 8;
#pragma unroll
    for (int kk = 0; kk < 32; ++kk) {
      w1[kk] = load_w8(p1 + kk * 32);
      w2[kk] = load_w8(p2 + kk * 32);
    }
    const float* q1 = Win1 + (size_t)hcol * kI + kq * 8;
    const float* q2 = Win2 + (size_t)hcol * kI + kq * 8;
#pragma unroll
    for (int kk = 0; kk < 8; ++kk) {
      wi1[kk] = load_w8(q1 + kk * 32);
      wi2[kk] = load_w8(q2 + kk * 32);
    }
  }
  const float bv1 = bin1[hcol];
  const float bv2 = bin2[hcol];
  fvec4 z2c0 = {0.f, 0.f, 0.f, 0.f}, z2c1 = {0.f, 0.f, 0.f, 0.f};

  // ---- prologue: stage X(0) -> Xbuf0, X(1) -> Xbuf1 ----
  {
    int r = tid >> 3, q = tid & 7;
#pragma unroll
    for (int p = 0; p < 2; ++p) {
      const float* xp = X + (size_t)(brow0 + r) * (kL * kI) + (size_t)p * kI;
      fvec4 xv[8];
#pragma unroll
      for (int j = 0; j < 8; ++j) xv[j] = *(const fvec4*)(xp + q * 4 + j * 32);
#pragma unroll
      for (int j = 0; j < 8; ++j) {
        int i0 = q * 4 + j * 32;
        ushort4 pk;
        pk.x = f2bf(xv[j][0]); pk.y = f2bf(xv[j][1]);
        pk.z = f2bf(xv[j][2]); pk.w = f2bf(xv[j][3]);
        *(ushort4*)(smem + 131072 + p * 16384 + (r << 9) + ((i0 * 2) ^ ((r & 7) << 4))) = pk;
      }
    }
  }
  __syncthreads();

  for (int l = 0; l < kL; ++l) {
    const bool even = ((l & 1) == 0);
    const int e = l >> 1;

    // ---- A1: issue z12 (and z2 on even) global->LDS, source-swizzled, dest linear ----
    {
      const unsigned short* zsrc = (l & 1) ? gbuf1 : gbuf0;
#pragma unroll
      for (int it = 0; it < 16; ++it) {
        int c = ((it * 4 + w) << 6) + lane;
        int r = c >> 7, cbs = (c & 127) * 16;
        gll16_coh((const char*)zsrc + (((size_t)(brow0 + r)) << 11) + (cbs ^ ((r & 7) << 4)),
                  smem + ((it * 4 + w) << 10));
      }
      if (even) {
        const unsigned short* z2src = (e & 1) ? z2b1 : z2b0;
#pragma unroll
        for (int it = 0; it < 16; ++it) {
          int c = ((it * 4 + w) << 6) + lane;
          int r = c >> 7, cbs = (c & 127) * 16;
          gll16_coh((const char*)z2src + (((size_t)(brow0 + r)) << 11) + (cbs ^ ((r & 7) << 4)),
                    smem + 65536 + ((it * 4 + w) << 10));
        }
      }
      __builtin_amdgcn_sched_barrier(0);  // keep issues above the MFMA shadow
    }

    // ---- A2: Win1*X(l) (+ Win2*X(l) on even) under the load shadow ----
    const char* xb = smem + 131072 + ((l & 1) << 14);
    fvec4 acc0 = {bv1, bv1, bv1, bv1}, acc1 = acc0;
#pragma unroll
    for (int kk = 0; kk < 8; ++kk) {
      int cb = kk * 64 + kq * 16;
      bhalf8 a0 = *(const bhalf8*)(xb + (row16 << 9) + (cb ^ sw));
      bhalf8 a1 = *(const bhalf8*)(xb + ((16 + row16) << 9) + (cb ^ sw));
      acc0 = MFMA16(a0, wi1[kk], acc0);
      acc1 = MFMA16(a1, wi1[kk], acc1);
    }
    fvec4 c2a0 = {bv2, bv2, bv2, bv2}, c2a1 = c2a0;
    if (even) {
#pragma unroll
      for (int kk = 0; kk < 8; ++kk) {
        int cb = kk * 64 + kq * 16;
        bhalf8 a0 = *(const bhalf8*)(xb + (row16 << 9) + (cb ^ sw));
        bhalf8 a1 = *(const bhalf8*)(xb + ((16 + row16) << 9) + (cb ^ sw));
        c2a0 = MFMA16(a0, wi2[kk], c2a0);
        c2a1 = MFMA16(a1, wi2[kk], c2a1);
      }
    }
    // ---- A3: staged data complete -> visible to all waves ----
    asm volatile("s_waitcnt vmcnt(0)" ::: "memory");
    __builtin_amdgcn_sched_barrier(0);
    __syncthreads();  // #1

    // ---- B1: z1 = tanh(acc + Wrec1 * z12) ----
#pragma unroll
    for (int kk = 0; kk < 32; ++kk) {
      int cb = kk * 64 + kq * 16;
      bhalf8 a0 = *(const bhalf8*)(smem + (row16 << 11) + (cb ^ sw));
      bhalf8 a1 = *(const bhalf8*)(smem + ((16 + row16) << 11) + (cb ^ sw));
      acc0 = MFMA16(a0, w1[kk], acc0);
      acc1 = MFMA16(a1, w1[kk], acc1);
    }
    fvec4 z1n0 = tanh4(acc0), z1n1 = tanh4(acc1);

    // ---- B2 (even): z2 = tanh(c2a + Wrec2 * z2prev) ----
    if (even) {
#pragma unroll
      for (int kk = 0; kk < 32; ++kk) {
        int cb = kk * 64 + kq * 16;
        bhalf8 a0 = *(const bhalf8*)(smem + 65536 + (row16 << 11) + (cb ^ sw));
        bhalf8 a1 = *(const bhalf8*)(smem + 65536 + ((16 + row16) << 11) + (cb ^ sw));
        c2a0 = MFMA16(a0, w2[kk], c2a0);
        c2a1 = MFMA16(a1, w2[kk], c2a1);
      }
      z2c0 = tanh4(c2a0);
      z2c1 = tanh4(c2a1);
    }

    // ---- C: publish z12 = z1+z2 (and z2 on even); drain; flag ----
    if (l < kL - 1) {
      unsigned short* dst = (l & 1) ? gbuf0 : gbuf1;
#pragma unroll
      for (int i = 0; i < 4; ++i) {
        st_short_coh(dst + (size_t)(brow0 + kq * 4 + i) * kH + hcol, f2bf(z1n0[i] + z2c0[i]));
        st_short_coh(dst + (size_t)(brow0 + 16 + kq * 4 + i) * kH + hcol, f2bf(z1n1[i] + z2c1[i]));
      }
    } else {
#pragma unroll
      for (int i = 0; i < 4; ++i) {
        st_f32_coh(z1buf + (size_t)(brow0 + kq * 4 + i) * kH + hcol, z1n0[i]);
        st_f32_coh(z1buf + (size_t)(brow0 + 16 + kq * 4 + i) * kH + hcol, z1n1[i]);
      }
    }
    if (even) {
      unsigned short* z2dst = (e & 1) ? z2b0 : z2b1;
#pragma unroll
      for (int i = 0; i < 4; ++i) {
        st_short_coh(z2dst + (size_t)(brow0 + kq * 4 + i) * kH + hcol, f2bf(z2c0[i]));
        st_short_coh(z2dst + (size_t)(brow0 + 16 + kq * 4 + i) * kH + hcol, f2bf(z2c1[i]));
      }
    }
    asm volatile("s_waitcnt vmcnt(0)" ::: "memory");
    __syncthreads();  // #2: all waves' exchange stores drained
    if (tid == 0) st_u32_coh(flags + grp * 16 + memb, (unsigned)(l + 1));

    // ---- D: X(l+2) -> Xbuf[l&1] (post-flag slack; normal cached loads) ----
    if (l + 2 < kL) {
      const int xr = tid >> 3, xq = tid & 7;
      const float* xp = X + (size_t)(brow0 + xr) * (kL * kI) + (size_t)(l + 2) * kI;
      fvec4 xv[8];
#pragma unroll
      for (int j = 0; j < 8; ++j) xv[j] = *(const fvec4*)(xp + xq * 4 + j * 32);
#pragma unroll
      for (int j = 0; j < 8; ++j) {
        int i0 = xq * 4 + j * 32;
        ushort4 pk;
        pk.x = f2bf(xv[j][0]); pk.y = f2bf(xv[j][1]);
        pk.z = f2bf(xv[j][2]); pk.w = f2bf(xv[j][3]);
        *(ushort4*)(smem + 131072 + ((l & 1) << 14) + (xr << 9) + ((i0 * 2) ^ ((xr & 7) << 4))) = pk;
      }
    }

    // ---- F: poll sibling flags for step l+1 ----
    {
      const unsigned tgt = (unsigned)(l + 1);
      const unsigned* fp = flags + grp * 16 + (lane & 15);
      for (;;) {
        unsigned v = (lane < 16) ? ld_u32_coh(fp) : tgt;
        bool ok = (lane >= 16) || ((lane & 15) == memb) || (v >= tgt);
        if (__all(ok)) break;
        __builtin_amdgcn_s_sleep(1);
      }
      __builtin_amdgcn_sched_barrier(0);
    }
  }

  // ---- epilogue: out[b] = tanh(z1[b,:] . Wout + bout), one WG per group ----
  // fused-vmcnt loads (rounds 4/7 proven; no deferred-load register window)
  if (memb == 0) {
    int r = tid >> 3, q = tid & 7;
    const float* zr = z1buf + (size_t)(brow0 + r) * kH;
    float s = 0.f;
    for (int h = q * 128; h < q * 128 + 128; ++h) s += ld_f32_coh(zr + h) * Wout[h];
    s += __shfl_xor(s, 1);
    s += __shfl_xor(s, 2);
    s += __shfl_xor(s, 4);
    if (q == 0) out[brow0 + r] = tanh_fast(s + bout[0]);
  }
}

extern "C" void kernel_launch(void* const* d_in, const int* in_sizes, int n_in,
                              void* d_out, int out_size, void* d_ws, size_t ws_size,
                              hipStream_t stream) {
  const float* X = (const float*)d_in[0];
  const float* Win1 = (const float*)d_in[1];
  const float* bin1 = (const float*)d_in[2];
  const float* Wrec1 = (const float*)d_in[3];
  const float* Win2 = (const float*)d_in[4];
  const float* bin2 = (const float*)d_in[5];
  const float* Wrec2 = (const float*)d_in[6];
  const float* Wout = (const float*)d_in[7];
  const float* bout = (const float*)d_in[8];
  float* out = (float*)d_out;

  char* ws = (char*)d_ws;
  unsigned* flags = (unsigned*)ws;                                   // 256 dwords
  unsigned short* gbuf0 = (unsigned short*)(ws + 4096);              // 1 MB z12 ping
  unsigned short* gbuf1 = (unsigned short*)(ws + 4096 + (1 << 20));  // 1 MB z12 pong
  unsigned short* z2b0 = (unsigned short*)(ws + 4096 + (2 << 20));   // 1 MB z2 ping
  unsigned short* z2b1 = (unsigned short*)(ws + 4096 + (3 << 20));   // 1 MB z2 pong
  float* z1buf = (float*)(ws + 4096 + (4 << 20));                    // 2 MB final z1 (f32)

  (void)hipMemsetAsync(flags, 0, 4096, stream);
  (void)hipMemsetAsync(gbuf0, 0, (size_t)512 * 1024 * 2, stream);  // z12(l=0) = 0
  (void)hipMemsetAsync(z2b0, 0, (size_t)512 * 1024 * 2, stream);   // z2(l=0)  = 0

  (void)hipFuncSetAttribute((const void*)alarm_rnn_persist,
                            hipFuncAttributeMaxDynamicSharedMemorySize, 163840);

  alarm_rnn_persist<<<dim3(256), dim3(256), 163840, stream>>>(
      X, Win1, bin1, Wrec1, Win2, bin2, Wrec2, Wout, bout, out,
      flags, gbuf0, gbuf1, z2b0, z2b1, z1buf);
}